// Round 7
// baseline (328.745 us; speedup 1.0000x reference)
//
#include <hip/hip_runtime.h>
#include <hip/hip_bf16.h>
#include <math.h>

typedef __bf16 bf16_8 __attribute__((ext_vector_type(8)));
typedef __bf16 bf16_4 __attribute__((ext_vector_type(4)));
typedef float f32x4 __attribute__((ext_vector_type(4)));

#define AS1 __attribute__((address_space(1)))
#define AS3 __attribute__((address_space(3)))

// ---------------------------------------------------------------- LayerNorm (fp32 in -> bf16 out)
__global__ __launch_bounds__(256) void ln_kernel(
    const float* __restrict__ x, const float* __restrict__ g,
    const float* __restrict__ b, __hip_bfloat16* __restrict__ out, int cols) {
  const int row = blockIdx.x;
  const int t = threadIdx.x;
  float loc[3];
  float s = 0.f, s2 = 0.f;
#pragma unroll
  for (int i = 0; i < 3; ++i) {
    float v = x[(size_t)row * cols + t + i * 256];
    loc[i] = v;
    s += v;
    s2 += v * v;
  }
#pragma unroll
  for (int off = 32; off; off >>= 1) {
    s += __shfl_down(s, off);
    s2 += __shfl_down(s2, off);
  }
  __shared__ float red[2][4];
  const int lane = t & 63, w = t >> 6;
  if (lane == 0) {
    red[0][w] = s;
    red[1][w] = s2;
  }
  __syncthreads();
  s = red[0][0] + red[0][1] + red[0][2] + red[0][3];
  s2 = red[1][0] + red[1][1] + red[1][2] + red[1][3];
  const float mu = s / cols;
  const float var = s2 / cols - mu * mu;
  const float rs = rsqrtf(var + 1e-5f);
  __hip_bfloat16* orow = out + (size_t)row * cols;
#pragma unroll
  for (int i = 0; i < 3; ++i) {
    int c = t + i * 256;
    orow[c] = __hip_bfloat16((loc[i] - mu) * rs * g[c] + b[c]);
  }
}

// ---------------------------------------------------------------- fused split-K reduce + residual + LN2
__global__ __launch_bounds__(256) void reduce_ln(
    const float* __restrict__ x, const float* __restrict__ part, int nz,
    const float* __restrict__ bias, const float* __restrict__ g,
    const float* __restrict__ b, float* __restrict__ res,
    __hip_bfloat16* __restrict__ yout) {
  const int row = blockIdx.x;
  const int t = threadIdx.x;
  const size_t zstride = (size_t)4096 * 768;
  float loc[3];
  float s = 0.f, s2 = 0.f;
#pragma unroll
  for (int i = 0; i < 3; ++i) {
    const int c = t + i * 256;
    const size_t off = (size_t)row * 768 + c;
    float v = x[off] + bias[c];
    for (int z = 0; z < nz; ++z) v += part[(size_t)z * zstride + off];
    res[off] = v;
    loc[i] = v;
    s += v;
    s2 += v * v;
  }
#pragma unroll
  for (int off = 32; off; off >>= 1) {
    s += __shfl_down(s, off);
    s2 += __shfl_down(s2, off);
  }
  __shared__ float red[2][4];
  const int lane = t & 63, w = t >> 6;
  if (lane == 0) {
    red[0][w] = s;
    red[1][w] = s2;
  }
  __syncthreads();
  s = red[0][0] + red[0][1] + red[0][2] + red[0][3];
  s2 = red[1][0] + red[1][1] + red[1][2] + red[1][3];
  const float mu = s / 768.f;
  const float var = s2 / 768.f - mu * mu;
  const float rs = rsqrtf(var + 1e-5f);
#pragma unroll
  for (int i = 0; i < 3; ++i) {
    const int c = t + i * 256;
    yout[(size_t)row * 768 + c] = __hip_bfloat16((loc[i] - mu) * rs * g[c] + b[c]);
  }
}

// ---------------------------------------------------------------- fused split-K reduce into residual (final out)
__global__ __launch_bounds__(256) void reduce_out(
    const float* __restrict__ part, int nz, const float* __restrict__ bias,
    float* __restrict__ res) {
  const int row = blockIdx.x;
  const int t = threadIdx.x;
  const size_t zstride = (size_t)4096 * 768;
#pragma unroll
  for (int i = 0; i < 3; ++i) {
    const int c = t + i * 256;
    const size_t off = (size_t)row * 768 + c;
    float v = res[off] + bias[c];
    for (int z = 0; z < nz; ++z) v += part[(size_t)z * zstride + off];
    res[off] = v;
  }
}

// ---------------------------------------------------------------- fp32 -> bf16 weight conversion
__global__ __launch_bounds__(256) void cvt_multi(
    const float* __restrict__ sa, const float* __restrict__ sb,
    const float* __restrict__ sc, const float* __restrict__ sd,
    __hip_bfloat16* __restrict__ da, __hip_bfloat16* __restrict__ db,
    __hip_bfloat16* __restrict__ dc, __hip_bfloat16* __restrict__ dd) {
  const float* src;
  __hip_bfloat16* dst;
  if (blockIdx.y == 0) { src = sa; dst = da; }
  else if (blockIdx.y == 1) { src = sb; dst = db; }
  else if (blockIdx.y == 2) { src = sc; dst = dc; }
  else { src = sd; dst = dd; }
  const size_t i = ((size_t)blockIdx.x * 256 + threadIdx.x) * 4;
  float4 f = *(const float4*)(src + i);
  bf16_4 o;
  o[0] = (__bf16)f.x; o[1] = (__bf16)f.y; o[2] = (__bf16)f.z; o[3] = (__bf16)f.w;
  *(bf16_4*)((__bf16*)dst + i) = o;
}

// ---------------------------------------------------------------- V pre-transpose + key-permute (frozen)
__global__ __launch_bounds__(256) void transpose_v(
    const __hip_bfloat16* __restrict__ v, __hip_bfloat16* __restrict__ vt) {
  const int S = 2048, E = 768, H = 12;
  const int s0 = blockIdx.x * 64;
  const int bh = blockIdx.y;
  const int b = bh / H, h = bh - b * H;
  __shared__ __align__(16) __bf16 T[64 * 72];
  const int tid = threadIdx.x;
#pragma unroll
  for (int u = 0; u < 2; ++u) {
    int i = tid + u * 256;
    int sr = i >> 3, c = i & 7;
    *(bf16_8*)(&T[sr * 72 + c * 8]) =
        *(const bf16_8*)(v + ((size_t)b * S + s0 + sr) * E + h * 64 + c * 8);
  }
  __syncthreads();
#pragma unroll
  for (int u = 0; u < 2; ++u) {
    int i = tid + u * 256;
    int dr = i >> 3, kc = i & 7;
    bf16_8 o;
#pragma unroll
    for (int e = 0; e < 8; ++e) {
      int k = 32 * (kc >> 2) + 16 * (e >> 2) + 4 * (kc & 3) + (e & 3);
      o[e] = T[k * 72 + dr];
    }
    *(bf16_8*)(vt + ((size_t)bh * 64 + dr) * S + s0 + kc * 8) = o;
  }
}

// ---------------------------------------------------------------- GEMM (frozen from round 6)
template <int MODE, bool BF32>
__global__ __launch_bounds__(256) void gemm_bt(
    const __hip_bfloat16* __restrict__ A, const void* __restrict__ Bx,
    const float* __restrict__ bias, void* __restrict__ out,
    int M, int N, int K, int lda, int ldb, int ldout) {
  constexpr int BM = 128, BN = 128, BK = 64;
  constexpr int LDBP = BF32 ? 72 : BK;
  __shared__ __align__(16) __bf16 As[BM * BK];
  __shared__ __align__(16) __bf16 Bs[BN * LDBP];
  const int tid = threadIdx.x;
  const int m0 = blockIdx.y * BM;
  const int n0 = blockIdx.x * BN;
  const int wave = tid >> 6;
  const int lane = tid & 63;
  const int quad = lane >> 4;
  const int l16 = lane & 15;
  const int wm = (wave & 1) * 64;
  const int wn = (wave >> 1) * 64;

  int kbase = 0, kcnt = K;
  if constexpr (MODE == 2 || MODE == 3) {
    kcnt = K / gridDim.z;
    kbase = blockIdx.z * kcnt;
  }

  const int srow = lane >> 3;
  const int scol = ((lane & 7) ^ (srow & 7)) * 8;
  const __hip_bfloat16* Ap = A + (size_t)(m0 + wave * 8 + srow) * lda + kbase + scol;
  const __hip_bfloat16* Bpb = nullptr;
  const float* Bpf = nullptr;
  if constexpr (BF32)
    Bpf = (const float*)Bx;
  else
    Bpb = (const __hip_bfloat16*)Bx + (size_t)(n0 + wave * 8 + srow) * ldb + kbase + scol;

  f32x4 acc[4][4] = {};

  for (int k0 = 0; k0 < kcnt; k0 += BK) {
    __syncthreads();
#pragma unroll
    for (int u = 0; u < 4; ++u) {
      __builtin_amdgcn_global_load_lds(
          (const AS1 void*)(Ap + (size_t)(u * 32) * lda + k0),
          (AS3 void*)(&As[(u * 32 + wave * 8) * BK]), 16, 0, 0);
      if constexpr (!BF32)
        __builtin_amdgcn_global_load_lds(
            (const AS1 void*)(Bpb + (size_t)(u * 32) * ldb + k0),
            (AS3 void*)(&Bs[(u * 32 + wave * 8) * BK]), 16, 0, 0);
    }
    if constexpr (BF32) {
#pragma unroll
      for (int u = 0; u < 4; ++u) {
        int c = u * 256 + tid;
        int row = c >> 3, kc = c & 7;
        const float* src = Bpf + (size_t)(n0 + row) * ldb + kbase + k0 + kc * 8;
        float4 f0 = *(const float4*)src;
        float4 f1 = *(const float4*)(src + 4);
        bf16_8 bv;
        bv[0] = (__bf16)f0.x; bv[1] = (__bf16)f0.y; bv[2] = (__bf16)f0.z; bv[3] = (__bf16)f0.w;
        bv[4] = (__bf16)f1.x; bv[5] = (__bf16)f1.y; bv[6] = (__bf16)f1.z; bv[7] = (__bf16)f1.w;
        *(bf16_8*)(&Bs[row * LDBP + kc * 8]) = bv;
      }
    }
    __syncthreads();
#pragma unroll
    for (int kk = 0; kk < 2; ++kk) {
      bf16_8 af[4], bfr[4];
#pragma unroll
      for (int i = 0; i < 4; ++i)
        af[i] = *(const bf16_8*)(
            &As[(wm + i * 16 + l16) * BK + (((kk * 4 + quad) ^ (l16 & 7)) * 8)]);
#pragma unroll
      for (int j = 0; j < 4; ++j) {
        if constexpr (BF32)
          bfr[j] = *(const bf16_8*)(&Bs[(wn + j * 16 + l16) * LDBP + kk * 32 + quad * 8]);
        else
          bfr[j] = *(const bf16_8*)(
              &Bs[(wn + j * 16 + l16) * BK + (((kk * 4 + quad) ^ (l16 & 7)) * 8)]);
      }
#pragma unroll
      for (int i = 0; i < 4; ++i)
#pragma unroll
        for (int j = 0; j < 4; ++j)
          acc[i][j] =
              __builtin_amdgcn_mfma_f32_16x16x32_bf16(af[i], bfr[j], acc[i][j], 0, 0, 0);
    }
  }

#pragma unroll
  for (int i = 0; i < 4; ++i) {
#pragma unroll
    for (int j = 0; j < 4; ++j) {
#pragma unroll
      for (int r = 0; r < 4; ++r) {
        const int row = m0 + wm + i * 16 + quad * 4 + r;
        const int col = n0 + wn + j * 16 + l16;
        const float v = acc[i][j][r];
        if constexpr (MODE == 0) {
          const int tsel = n0 / 768;
          const size_t idx = ((size_t)tsel * M + row) * 768 + (col - tsel * 768);
          ((__hip_bfloat16*)out)[idx] = __hip_bfloat16(v);
        } else if constexpr (MODE == 1) {
          float tt = v + bias[col];
          float gl = 0.5f * tt * (1.0f + erff(tt * 0.70710678118654752f));
          ((__hip_bfloat16*)out)[(size_t)row * ldout + col] = __hip_bfloat16(gl);
        } else if constexpr (MODE == 2) {
          float add = v + ((blockIdx.z == 0 && bias) ? bias[col] : 0.f);
          atomicAdd((float*)out + (size_t)row * 768 + col, add);
        } else {
          ((float*)out)[(size_t)blockIdx.z * M * 768 + (size_t)row * 768 + col] = v;
        }
      }
    }
  }
}

// ---------------------------------------------------------------- work counter
__global__ void zero_ctr(int* __restrict__ c) {
  if (threadIdx.x == 0) *c = 0;
}

// ---------------------------------------------------------------- MFMA flash attention, v4: KV-split
// Inner loop frozen from round 5/6 (in-register P, exp2 softmax, dbuf, 1 barrier/tile).
// NEW: for qblk >= 16 the KV range splits into two tasks (flash-decoding style); each
// writes unnormalized O^T partials + per-q (m,l); attn_combine merges. This halves the
// serial KV chain of the heaviest tasks (makespan 32 -> <=17 tiles).
#define ALDP 72
// 48-unit schedule (qblk, part) sorted by descending tile count; part 2 = full range.
__device__ __constant__ signed char UQ[48] = {
    31, 31, 30, 15, 30, 29, 29, 28, 14, 28, 27, 27, 26, 13, 26, 25,
    25, 24, 12, 24, 23, 23, 22, 11, 22, 21, 21, 20, 10, 20, 19, 19,
    18, 9, 18, 17, 17, 16, 8, 16, 7, 6, 5, 4, 3, 2, 1, 0};
__device__ __constant__ signed char UP[48] = {
    0, 1, 1, 2, 0, 0, 1, 1, 2, 0, 0, 1, 1, 2, 0, 0,
    1, 1, 2, 0, 0, 1, 1, 2, 0, 0, 1, 1, 2, 0, 0, 1,
    1, 2, 0, 0, 1, 1, 2, 0, 2, 2, 2, 2, 2, 2, 2, 2};

template <bool PRE_T, bool SPLIT>
__global__ __launch_bounds__(256) void attn_mfma(
    const __hip_bfloat16* __restrict__ qb, const __hip_bfloat16* __restrict__ kb,
    const __hip_bfloat16* __restrict__ vb, __hip_bfloat16* __restrict__ ob,
    float* __restrict__ po, float* __restrict__ pml, int* __restrict__ ctr) {
  const int S = 2048, H = 12, E = 768;
  const int tid = threadIdx.x;
  const int wave = tid >> 6;
  const int lane = tid & 63;
  const int quad = lane >> 4;
  const int l16 = lane & 15;

  __shared__ __align__(16) __bf16 Ks[2][64 * 64];  // [key][d], chunk-XOR swizzled
  __shared__ __align__(16) __bf16 Vt[2][64 * 64];  // [d][key-permuted], swizzled
  __shared__ int task;
  __bf16* ep = &Ks[0][0] + wave * 16 * ALDP;  // epilogue buffer aliases Ks

  const int srow8 = lane >> 3;
  const int csrc = ((lane & 7) ^ srow8) * 8;
  const float SCL = 0.18033688011112042f;  // (1/sqrt(64)) * log2(e)
  const int NTASK = SPLIT ? 24 * 48 : 24 * 32;

  for (;;) {
    if (tid == 0) task = atomicAdd(ctr, 1);
    __syncthreads();
    const int t = task;
    if (t >= NTASK) return;
    int qblk, part, bh;
    if constexpr (SPLIT) {
      const int unit = t / 24;
      bh = t - unit * 24;
      qblk = UQ[unit];
      part = UP[unit];
    } else {
      qblk = 31 - (t / 24);
      bh = t - (t / 24) * 24;
      part = 2;
    }
    const int b = bh / H, h = bh - b * H;
    const int q0 = qblk * 64;
    const int qw = q0 + wave * 16;
    const size_t base = (size_t)b * S * E + (size_t)h * 64;
    const int mid = (qblk + 1) >> 1;
    const int kbgn = (part == 1) ? mid : 0;
    const int kend = (part == 0) ? mid : qblk + 1;

    auto STAGE = [&](int kts, int buf) {
      const int k0s = kts * 64;
#pragma unroll
      for (int u = 0; u < 2; ++u) {
        const int trow = wave * 16 + u * 8;
        __builtin_amdgcn_global_load_lds(
            (const AS1 void*)(kb + base + (size_t)(k0s + trow + srow8) * E + csrc),
            (AS3 void*)(&Ks[buf][trow * 64]), 16, 0, 0);
        if constexpr (PRE_T)
          __builtin_amdgcn_global_load_lds(
              (const AS1 void*)(vb + ((size_t)(bh * 64 + trow + srow8)) * S + k0s + csrc),
              (AS3 void*)(&Vt[buf][trow * 64]), 16, 0, 0);
      }
      if constexpr (!PRE_T) {
#pragma unroll
        for (int u = 0; u < 2; ++u) {
          int i = tid + u * 256;
          int kr = i & 63, dq = i >> 6;
          bf16_8 vv = *(const bf16_8*)(vb + base + (size_t)(k0s + kr) * E + dq * 8);
          const int c = 32 * (kr >> 5) + 8 * ((kr >> 2) & 3) + 4 * ((kr >> 4) & 1) + (kr & 3);
#pragma unroll
          for (int j = 0; j < 8; ++j) {
            int drow = dq * 8 + j;
            Vt[buf][drow * 64 + (((c >> 3) ^ (drow & 7)) * 8) + (c & 7)] = vv[j];
          }
        }
      }
    };

    bf16_8 qf[2];
#pragma unroll
    for (int s = 0; s < 2; ++s)
      qf[s] = *(const bf16_8*)(qb + base + (size_t)(qw + l16) * E + s * 32 + quad * 8);

    f32x4 o[4] = {};
    float mq = -1e30f, lq = 0.f;

    STAGE(kbgn, 0);
    __syncthreads();
    int cur = 0;

    for (int kt = kbgn; kt < kend; ++kt) {
      const int k0 = kt * 64;
      if (kt + 1 < kend) STAGE(kt + 1, cur ^ 1);

      f32x4 sc[4] = {};
      __builtin_amdgcn_s_setprio(1);
#pragma unroll
      for (int jj = 0; jj < 4; ++jj)
#pragma unroll
        for (int s = 0; s < 2; ++s) {
          bf16_8 kf = *(const bf16_8*)(
              &Ks[cur][(jj * 16 + l16) * 64 + (((s * 4 + quad) ^ (l16 & 7)) * 8)]);
          sc[jj] = __builtin_amdgcn_mfma_f32_16x16x32_bf16(kf, qf[s], sc[jj], 0, 0, 0);
        }
      __builtin_amdgcn_s_setprio(0);

#pragma unroll
      for (int jj = 0; jj < 4; ++jj)
#pragma unroll
        for (int r = 0; r < 4; ++r) sc[jj][r] *= SCL;
      if (kt == qblk) {
#pragma unroll
        for (int jj = 0; jj < 4; ++jj)
#pragma unroll
          for (int r = 0; r < 4; ++r)
            if ((k0 + jj * 16 + quad * 4 + r) > (qw + l16)) sc[jj][r] = -1e30f;
      }
      float mj[4];
#pragma unroll
      for (int jj = 0; jj < 4; ++jj)
        mj[jj] = fmaxf(fmaxf(sc[jj][0], sc[jj][1]), fmaxf(sc[jj][2], sc[jj][3]));
      float mx = fmaxf(fmaxf(mj[0], mj[1]), fmaxf(mj[2], mj[3]));
      mx = fmaxf(mx, __shfl_xor(mx, 16));
      mx = fmaxf(mx, __shfl_xor(mx, 32));
      const float mn = fmaxf(mq, mx);
      const float corr = exp2f(mq - mn);
      mq = mn;
      float sj[4];
#pragma unroll
      for (int jj = 0; jj < 4; ++jj) {
#pragma unroll
        for (int r = 0; r < 4; ++r) sc[jj][r] = exp2f(sc[jj][r] - mn);
        sj[jj] = (sc[jj][0] + sc[jj][1]) + (sc[jj][2] + sc[jj][3]);
      }
      float sum = (sj[0] + sj[1]) + (sj[2] + sj[3]);
      sum += __shfl_xor(sum, 16);
      sum += __shfl_xor(sum, 32);
      lq = lq * corr + sum;
#pragma unroll
      for (int nt2 = 0; nt2 < 4; ++nt2)
#pragma unroll
        for (int r = 0; r < 4; ++r) o[nt2][r] *= corr;

      bf16_8 pf[2];
#pragma unroll
      for (int s = 0; s < 2; ++s)
#pragma unroll
        for (int r = 0; r < 4; ++r) {
          pf[s][r] = (__bf16)sc[2 * s][r];
          pf[s][4 + r] = (__bf16)sc[2 * s + 1][r];
        }

      __builtin_amdgcn_s_setprio(1);
#pragma unroll
      for (int s = 0; s < 2; ++s)
#pragma unroll
        for (int dt = 0; dt < 4; ++dt) {
          bf16_8 vf = *(const bf16_8*)(
              &Vt[cur][(dt * 16 + l16) * 64 + (((s * 4 + quad) ^ (l16 & 7)) * 8)]);
          o[dt] = __builtin_amdgcn_mfma_f32_16x16x32_bf16(vf, pf[s], o[dt], 0, 0, 0);
        }
      __builtin_amdgcn_s_setprio(0);

      __syncthreads();
      cur ^= 1;
    }

    if (SPLIT && part != 2) {
      // write unnormalized O^T partial + (m,l): po[cidx][part][d=64][q=64] f32
      const int cidx = bh * 16 + (qblk - 16);
      float* poT = po + (size_t)cidx * 8192 + part * 4096;
      const int ql = wave * 16 + l16;
#pragma unroll
      for (int dt = 0; dt < 4; ++dt)
#pragma unroll
        for (int r = 0; r < 4; ++r)
          poT[(dt * 16 + quad * 4 + r) * 64 + ql] = o[dt][r];
      if (quad == 0) {
        pml[(size_t)cidx * 256 + part * 128 + ql] = mq;
        pml[(size_t)cidx * 256 + part * 128 + 64 + ql] = lq;
      }
    } else {
      // normalized write via LDS transpose (ep aliases Ks; safe after final barrier)
      const float inv = 1.f / lq;
#pragma unroll
      for (int dt = 0; dt < 4; ++dt) {
        bf16_4 o4;
#pragma unroll
        for (int r = 0; r < 4; ++r) o4[r] = (__bf16)(o[dt][r] * inv);
        *(bf16_4*)(&ep[l16 * ALDP + dt * 16 + quad * 4]) = o4;
      }
#pragma unroll
      for (int u = 0; u < 2; ++u) {
        int j = lane + u * 64;
        int ql = j >> 3, ch = j & 7;
        bf16_8 ov = *(const bf16_8*)(&ep[ql * ALDP + ch * 8]);
        *(bf16_8*)(ob + base + (size_t)(qw + ql) * E + ch * 8) = ov;
      }
    }
  }
}

// ---------------------------------------------------------------- combine split-KV partials
// grid = 24*16 blocks; block cidx -> (bh = cidx/16, qblk = 16 + cidx%16).
__global__ __launch_bounds__(256) void attn_combine(
    const float* __restrict__ po, const float* __restrict__ pml,
    __hip_bfloat16* __restrict__ ob) {
  const int S = 2048, H = 12, E = 768;
  const int cidx = blockIdx.x;
  const int bh = cidx / 16;
  const int qblk = 16 + (cidx - bh * 16);
  const int b = bh / H, h = bh - b * H;
  const int q0 = qblk * 64;
  const size_t base = (size_t)b * S * E + (size_t)h * 64;
  const float* P0 = po + (size_t)cidx * 8192;
  const float* P1 = P0 + 4096;
  const float* ML = pml + (size_t)cidx * 256;

  __shared__ float a1[64], a2[64], dn[64];
  const int t = threadIdx.x;
  if (t < 64) {
    const float m1 = ML[t], l1 = ML[64 + t];
    const float m2 = ML[128 + t], l2 = ML[192 + t];
    const float ms = fmaxf(m1, m2);
    const float e1 = exp2f(m1 - ms), e2 = exp2f(m2 - ms);
    a1[t] = e1;
    a2[t] = e2;
    dn[t] = 1.f / (e1 * l1 + e2 * l2);
  }
  __syncthreads();
  const int d = t & 63;
  const int qg = t >> 6;  // 4 q per pass
#pragma unroll
  for (int i = 0; i < 16; ++i) {
    const int q = qg + i * 4;
    const float v = (a1[q] * P0[d * 64 + q] + a2[q] * P1[d * 64 + q]) * dn[q];
    ob[base + (size_t)(q0 + q) * E + d] = __hip_bfloat16(v);
  }
}

// ---------------------------------------------------------------- launch
extern "C" void kernel_launch(void* const* d_in, const int* in_sizes, int n_in,
                              void* d_out, int out_size, void* d_ws, size_t ws_size,
                              hipStream_t stream) {
  const int Bv = 2, S = 2048, E = 768, FF = 3072;
  const int M = Bv * S;  // 4096
  const size_t ME = (size_t)M * E;
  const size_t EE = (size_t)E * E;
  const size_t EF = (size_t)E * FF;

  const float* x = (const float*)d_in[0];
  const float* wq = (const float*)d_in[1];
  const float* wk = (const float*)d_in[2];
  const float* wv = (const float*)d_in[3];
  const float* wo = (const float*)d_in[4];
  const float* bo = (const float*)d_in[5];
  const float* w1 = (const float*)d_in[6];
  const float* b1 = (const float*)d_in[7];
  const float* w2 = (const float*)d_in[8];
  const float* b2 = (const float*)d_in[9];
  const float* gamma = (const float*)d_in[10];
  const float* beta = (const float*)d_in[11];

  // ws: [ctr+256B][s0..s4: 5×ME bf16][s5: w1|w2 bf16 2×EF][pp: 4×ME fp32]
  // Within pp (50.3 MB), attention phase time-shares: vt (ME bf16 = 6.3 MB),
  // po (384×8192 f32 = 12.6 MB), pml (384×256 f32 = 0.4 MB). All dead before
  // GEMM partials reuse pp.
  int* ctr = (int*)d_ws;
  __hip_bfloat16* slot = (__hip_bfloat16*)((char*)d_ws + 256);
  __hip_bfloat16* s0 = slot;
  __hip_bfloat16* s1 = slot + ME;
  __hip_bfloat16* s4 = slot + 4 * ME;
  __hip_bfloat16* s5 = slot + 5 * ME;
  float* pp = (float*)(slot + 5 * ME + 2 * EF);
  __hip_bfloat16* vt = (__hip_bfloat16*)pp;
  float* po = (float*)((char*)pp + ME * sizeof(__hip_bfloat16));
  float* pml = po + (size_t)384 * 8192;
  float* res = (float*)d_out;

  const size_t need_mid = 256 + (5 * ME + 2 * EF) * sizeof(__hip_bfloat16);
  const size_t need_full = need_mid + 4 * ME * sizeof(float);
  const bool full = ws_size >= need_full;
  const bool mid = ws_size >= need_mid;

  // 0. weights -> bf16
  cvt_multi<<<dim3(EE / 1024, 4), 256, 0, stream>>>(
      wq, wk, wv, wo, s4, s4 + EE, s4 + 2 * EE, s4 + 3 * EE);
  if (mid)
    cvt_multi<<<dim3(EF / 1024, 2), 256, 0, stream>>>(
        w1, w2, nullptr, nullptr, s5, s5 + EF, nullptr, nullptr);
  // 1. LN1
  ln_kernel<<<M, 256, 0, stream>>>(x, gamma, beta, s0, E);
  // 2. fused Q/K/V projection -> s1,s2,s3
  gemm_bt<0, false><<<dim3(18, 32), 256, 0, stream>>>(s0, s4, nullptr, s1, M, 2304, E, E, E, 0);
  // 3. causal flash attention -> s0 (+ split partials -> po/pml, combined after)
  zero_ctr<<<1, 64, 0, stream>>>(ctr);
  if (full) {
    transpose_v<<<dim3(32, 24), 256, 0, stream>>>(s1 + 2 * ME, vt);
    attn_mfma<true, true><<<1024, 256, 0, stream>>>(s1, s1 + ME, vt, s0, po, pml, ctr);
    attn_combine<<<384, 256, 0, stream>>>(po, pml, s0);
  } else {
    attn_mfma<false, false><<<768, 256, 0, stream>>>(
        s1, s1 + ME, s1 + 2 * ME, s0, nullptr, nullptr, ctr);
  }

  if (full) {
    // 4. attn-proj partials z=4
    gemm_bt<3, false><<<dim3(6, 32, 4), 256, 0, stream>>>(
        s0, s4 + 3 * EE, nullptr, pp, M, E, E, E, E, 0);
    // 5. res = x + Σpp + bo; y = LN2(res) -> s0
    reduce_ln<<<M, 256, 0, stream>>>(x, pp, 4, bo, gamma, beta, res, s0);
    // 6. FFN up + GELU -> s1..s4
    gemm_bt<1, false><<<dim3(24, 32), 256, 0, stream>>>(s0, s5, b1, s1, M, FF, E, E, E, FF);
    // 7. FFN down partials z=4
    gemm_bt<3, false><<<dim3(6, 32, 4), 256, 0, stream>>>(
        s1, s5 + EF, nullptr, pp, M, E, FF, FF, FF, 0);
    // 8. out = res + Σpp + b2
    reduce_out<<<M, 256, 0, stream>>>(pp, 4, b2, res);
  } else {
    hipMemcpyAsync(d_out, x, ME * sizeof(float), hipMemcpyDeviceToDevice, stream);
    gemm_bt<2, false><<<dim3(6, 32, 2), 256, 0, stream>>>(
        s0, s4 + 3 * EE, bo, res, M, E, E, E, E, 0);
    ln_kernel<<<M, 256, 0, stream>>>(res, gamma, beta, s0, E);
    if (mid) {
      gemm_bt<1, false><<<dim3(24, 32), 256, 0, stream>>>(s0, s5, b1, s1, M, FF, E, E, E, FF);
      gemm_bt<2, false><<<dim3(6, 32, 4), 256, 0, stream>>>(
          s1, s5 + EF, b2, res, M, E, FF, FF, FF, 0);
    } else {
      gemm_bt<1, true><<<dim3(24, 32), 256, 0, stream>>>(s0, w1, b1, s1, M, FF, E, E, E, FF);
      cvt_multi<<<dim3(EF / 1024, 1), 256, 0, stream>>>(
          w2, nullptr, nullptr, nullptr, s0, nullptr, nullptr, nullptr);
      gemm_bt<2, false><<<dim3(6, 32, 4), 256, 0, stream>>>(
          s1, s0, b2, res, M, E, FF, FF, FF, 0);
    }
  }
}

// Round 8
// 317.589 us; speedup vs baseline: 1.0351x; 1.0351x over previous
//
#include <hip/hip_runtime.h>
#include <hip/hip_bf16.h>
#include <math.h>

typedef __bf16 bf16_8 __attribute__((ext_vector_type(8)));
typedef __bf16 bf16_4 __attribute__((ext_vector_type(4)));
typedef float f32x4 __attribute__((ext_vector_type(4)));

#define AS1 __attribute__((address_space(1)))
#define AS3 __attribute__((address_space(3)))

// ---------------------------------------------------------------- LayerNorm (fp32 in -> bf16 out)
__global__ __launch_bounds__(256) void ln_kernel(
    const float* __restrict__ x, const float* __restrict__ g,
    const float* __restrict__ b, __hip_bfloat16* __restrict__ out, int cols) {
  const int row = blockIdx.x;
  const int t = threadIdx.x;
  float loc[3];
  float s = 0.f, s2 = 0.f;
#pragma unroll
  for (int i = 0; i < 3; ++i) {
    float v = x[(size_t)row * cols + t + i * 256];
    loc[i] = v;
    s += v;
    s2 += v * v;
  }
#pragma unroll
  for (int off = 32; off; off >>= 1) {
    s += __shfl_down(s, off);
    s2 += __shfl_down(s2, off);
  }
  __shared__ float red[2][4];
  const int lane = t & 63, w = t >> 6;
  if (lane == 0) {
    red[0][w] = s;
    red[1][w] = s2;
  }
  __syncthreads();
  s = red[0][0] + red[0][1] + red[0][2] + red[0][3];
  s2 = red[1][0] + red[1][1] + red[1][2] + red[1][3];
  const float mu = s / cols;
  const float var = s2 / cols - mu * mu;
  const float rs = rsqrtf(var + 1e-5f);
  __hip_bfloat16* orow = out + (size_t)row * cols;
#pragma unroll
  for (int i = 0; i < 3; ++i) {
    int c = t + i * 256;
    orow[c] = __hip_bfloat16((loc[i] - mu) * rs * g[c] + b[c]);
  }
}

// ---------------------------------------------------------------- fused split-K reduce + residual + LN2
__global__ __launch_bounds__(256) void reduce_ln(
    const float* __restrict__ x, const float* __restrict__ part, int nz,
    const float* __restrict__ bias, const float* __restrict__ g,
    const float* __restrict__ b, float* __restrict__ res,
    __hip_bfloat16* __restrict__ yout) {
  const int row = blockIdx.x;
  const int t = threadIdx.x;
  const size_t zstride = (size_t)4096 * 768;
  float loc[3];
  float s = 0.f, s2 = 0.f;
#pragma unroll
  for (int i = 0; i < 3; ++i) {
    const int c = t + i * 256;
    const size_t off = (size_t)row * 768 + c;
    float v = x[off] + bias[c];
    for (int z = 0; z < nz; ++z) v += part[(size_t)z * zstride + off];
    res[off] = v;
    loc[i] = v;
    s += v;
    s2 += v * v;
  }
#pragma unroll
  for (int off = 32; off; off >>= 1) {
    s += __shfl_down(s, off);
    s2 += __shfl_down(s2, off);
  }
  __shared__ float red[2][4];
  const int lane = t & 63, w = t >> 6;
  if (lane == 0) {
    red[0][w] = s;
    red[1][w] = s2;
  }
  __syncthreads();
  s = red[0][0] + red[0][1] + red[0][2] + red[0][3];
  s2 = red[1][0] + red[1][1] + red[1][2] + red[1][3];
  const float mu = s / 768.f;
  const float var = s2 / 768.f - mu * mu;
  const float rs = rsqrtf(var + 1e-5f);
#pragma unroll
  for (int i = 0; i < 3; ++i) {
    const int c = t + i * 256;
    yout[(size_t)row * 768 + c] = __hip_bfloat16((loc[i] - mu) * rs * g[c] + b[c]);
  }
}

// ---------------------------------------------------------------- fused split-K reduce into residual (final out)
__global__ __launch_bounds__(256) void reduce_out(
    const float* __restrict__ part, int nz, const float* __restrict__ bias,
    float* __restrict__ res) {
  const int row = blockIdx.x;
  const int t = threadIdx.x;
  const size_t zstride = (size_t)4096 * 768;
#pragma unroll
  for (int i = 0; i < 3; ++i) {
    const int c = t + i * 256;
    const size_t off = (size_t)row * 768 + c;
    float v = res[off] + bias[c];
    for (int z = 0; z < nz; ++z) v += part[(size_t)z * zstride + off];
    res[off] = v;
  }
}

// ---------------------------------------------------------------- fp32 -> bf16 weight conversion
__global__ __launch_bounds__(256) void cvt_multi(
    const float* __restrict__ sa, const float* __restrict__ sb,
    const float* __restrict__ sc, const float* __restrict__ sd,
    __hip_bfloat16* __restrict__ da, __hip_bfloat16* __restrict__ db,
    __hip_bfloat16* __restrict__ dc, __hip_bfloat16* __restrict__ dd) {
  const float* src;
  __hip_bfloat16* dst;
  if (blockIdx.y == 0) { src = sa; dst = da; }
  else if (blockIdx.y == 1) { src = sb; dst = db; }
  else if (blockIdx.y == 2) { src = sc; dst = dc; }
  else { src = sd; dst = dd; }
  const size_t i = ((size_t)blockIdx.x * 256 + threadIdx.x) * 4;
  float4 f = *(const float4*)(src + i);
  bf16_4 o;
  o[0] = (__bf16)f.x; o[1] = (__bf16)f.y; o[2] = (__bf16)f.z; o[3] = (__bf16)f.w;
  *(bf16_4*)((__bf16*)dst + i) = o;
}

// ---------------------------------------------------------------- V pre-transpose + key-permute (frozen)
__global__ __launch_bounds__(256) void transpose_v(
    const __hip_bfloat16* __restrict__ v, __hip_bfloat16* __restrict__ vt) {
  const int S = 2048, E = 768, H = 12;
  const int s0 = blockIdx.x * 64;
  const int bh = blockIdx.y;
  const int b = bh / H, h = bh - b * H;
  __shared__ __align__(16) __bf16 T[64 * 72];
  const int tid = threadIdx.x;
#pragma unroll
  for (int u = 0; u < 2; ++u) {
    int i = tid + u * 256;
    int sr = i >> 3, c = i & 7;
    *(bf16_8*)(&T[sr * 72 + c * 8]) =
        *(const bf16_8*)(v + ((size_t)b * S + s0 + sr) * E + h * 64 + c * 8);
  }
  __syncthreads();
#pragma unroll
  for (int u = 0; u < 2; ++u) {
    int i = tid + u * 256;
    int dr = i >> 3, kc = i & 7;
    bf16_8 o;
#pragma unroll
    for (int e = 0; e < 8; ++e) {
      int k = 32 * (kc >> 2) + 16 * (e >> 2) + 4 * (kc & 3) + (e & 3);
      o[e] = T[k * 72 + dr];
    }
    *(bf16_8*)(vt + ((size_t)bh * 64 + dr) * S + s0 + kc * 8) = o;
  }
}

// ---------------------------------------------------------------- GEMM (frozen from round 6)
template <int MODE, bool BF32>
__global__ __launch_bounds__(256) void gemm_bt(
    const __hip_bfloat16* __restrict__ A, const void* __restrict__ Bx,
    const float* __restrict__ bias, void* __restrict__ out,
    int M, int N, int K, int lda, int ldb, int ldout) {
  constexpr int BM = 128, BN = 128, BK = 64;
  constexpr int LDBP = BF32 ? 72 : BK;
  __shared__ __align__(16) __bf16 As[BM * BK];
  __shared__ __align__(16) __bf16 Bs[BN * LDBP];
  const int tid = threadIdx.x;
  const int m0 = blockIdx.y * BM;
  const int n0 = blockIdx.x * BN;
  const int wave = tid >> 6;
  const int lane = tid & 63;
  const int quad = lane >> 4;
  const int l16 = lane & 15;
  const int wm = (wave & 1) * 64;
  const int wn = (wave >> 1) * 64;

  int kbase = 0, kcnt = K;
  if constexpr (MODE == 2 || MODE == 3) {
    kcnt = K / gridDim.z;
    kbase = blockIdx.z * kcnt;
  }

  const int srow = lane >> 3;
  const int scol = ((lane & 7) ^ (srow & 7)) * 8;
  const __hip_bfloat16* Ap = A + (size_t)(m0 + wave * 8 + srow) * lda + kbase + scol;
  const __hip_bfloat16* Bpb = nullptr;
  const float* Bpf = nullptr;
  if constexpr (BF32)
    Bpf = (const float*)Bx;
  else
    Bpb = (const __hip_bfloat16*)Bx + (size_t)(n0 + wave * 8 + srow) * ldb + kbase + scol;

  f32x4 acc[4][4] = {};

  for (int k0 = 0; k0 < kcnt; k0 += BK) {
    __syncthreads();
#pragma unroll
    for (int u = 0; u < 4; ++u) {
      __builtin_amdgcn_global_load_lds(
          (const AS1 void*)(Ap + (size_t)(u * 32) * lda + k0),
          (AS3 void*)(&As[(u * 32 + wave * 8) * BK]), 16, 0, 0);
      if constexpr (!BF32)
        __builtin_amdgcn_global_load_lds(
            (const AS1 void*)(Bpb + (size_t)(u * 32) * ldb + k0),
            (AS3 void*)(&Bs[(u * 32 + wave * 8) * BK]), 16, 0, 0);
    }
    if constexpr (BF32) {
#pragma unroll
      for (int u = 0; u < 4; ++u) {
        int c = u * 256 + tid;
        int row = c >> 3, kc = c & 7;
        const float* src = Bpf + (size_t)(n0 + row) * ldb + kbase + k0 + kc * 8;
        float4 f0 = *(const float4*)src;
        float4 f1 = *(const float4*)(src + 4);
        bf16_8 bv;
        bv[0] = (__bf16)f0.x; bv[1] = (__bf16)f0.y; bv[2] = (__bf16)f0.z; bv[3] = (__bf16)f0.w;
        bv[4] = (__bf16)f1.x; bv[5] = (__bf16)f1.y; bv[6] = (__bf16)f1.z; bv[7] = (__bf16)f1.w;
        *(bf16_8*)(&Bs[row * LDBP + kc * 8]) = bv;
      }
    }
    __syncthreads();
#pragma unroll
    for (int kk = 0; kk < 2; ++kk) {
      bf16_8 af[4], bfr[4];
#pragma unroll
      for (int i = 0; i < 4; ++i)
        af[i] = *(const bf16_8*)(
            &As[(wm + i * 16 + l16) * BK + (((kk * 4 + quad) ^ (l16 & 7)) * 8)]);
#pragma unroll
      for (int j = 0; j < 4; ++j) {
        if constexpr (BF32)
          bfr[j] = *(const bf16_8*)(&Bs[(wn + j * 16 + l16) * LDBP + kk * 32 + quad * 8]);
        else
          bfr[j] = *(const bf16_8*)(
              &Bs[(wn + j * 16 + l16) * BK + (((kk * 4 + quad) ^ (l16 & 7)) * 8)]);
      }
#pragma unroll
      for (int i = 0; i < 4; ++i)
#pragma unroll
        for (int j = 0; j < 4; ++j)
          acc[i][j] =
              __builtin_amdgcn_mfma_f32_16x16x32_bf16(af[i], bfr[j], acc[i][j], 0, 0, 0);
    }
  }

#pragma unroll
  for (int i = 0; i < 4; ++i) {
#pragma unroll
    for (int j = 0; j < 4; ++j) {
#pragma unroll
      for (int r = 0; r < 4; ++r) {
        const int row = m0 + wm + i * 16 + quad * 4 + r;
        const int col = n0 + wn + j * 16 + l16;
        const float v = acc[i][j][r];
        if constexpr (MODE == 0) {
          const int tsel = n0 / 768;
          const size_t idx = ((size_t)tsel * M + row) * 768 + (col - tsel * 768);
          ((__hip_bfloat16*)out)[idx] = __hip_bfloat16(v);
        } else if constexpr (MODE == 1) {
          float tt = v + bias[col];
          float gl = 0.5f * tt * (1.0f + erff(tt * 0.70710678118654752f));
          ((__hip_bfloat16*)out)[(size_t)row * ldout + col] = __hip_bfloat16(gl);
        } else if constexpr (MODE == 2) {
          float add = v + ((blockIdx.z == 0 && bias) ? bias[col] : 0.f);
          atomicAdd((float*)out + (size_t)row * 768 + col, add);
        } else {
          ((float*)out)[(size_t)blockIdx.z * M * 768 + (size_t)row * 768 + col] = v;
        }
      }
    }
  }
}

// ---------------------------------------------------------------- work counter
__global__ void zero_ctr(int* __restrict__ c) {
  if (threadIdx.x == 0) *c = 0;
}

// ---------------------------------------------------------------- MFMA flash attention, v5: KV-split + 6 blocks/CU
// Inner math frozen (in-register P, exp2 softmax). NEW schedule: single-buffered K
// (8 KB) + double-buffered V^T (16 KB) -> LDS 24.6 KB -> 6 blocks/CU (was 4).
// Per tile: QK^T -> barrier#1 (no outstanding vm, cheap) -> stage K(next)+V(next)
// -> softmax+PV (covers HBM latency) -> barrier#2 (drain). Hazards: Ks overwrite
// only after barrier#1; Vt[cur^1] last read one barrier earlier; all stage reads
// gated by barrier#2's implicit vmcnt(0).
#define ALDP 72
__device__ __constant__ signed char UQ[48] = {
    31, 31, 30, 15, 30, 29, 29, 28, 14, 28, 27, 27, 26, 13, 26, 25,
    25, 24, 12, 24, 23, 23, 22, 11, 22, 21, 21, 20, 10, 20, 19, 19,
    18, 9, 18, 17, 17, 16, 8, 16, 7, 6, 5, 4, 3, 2, 1, 0};
__device__ __constant__ signed char UP[48] = {
    0, 1, 1, 2, 0, 0, 1, 1, 2, 0, 0, 1, 1, 2, 0, 0,
    1, 1, 2, 0, 0, 1, 1, 2, 0, 0, 1, 1, 2, 0, 0, 1,
    1, 2, 0, 0, 1, 1, 2, 0, 2, 2, 2, 2, 2, 2, 2, 2};

template <bool PRE_T, bool SPLIT>
__global__ __launch_bounds__(256) void attn_mfma(
    const __hip_bfloat16* __restrict__ qb, const __hip_bfloat16* __restrict__ kb,
    const __hip_bfloat16* __restrict__ vb, __hip_bfloat16* __restrict__ ob,
    float* __restrict__ po, float* __restrict__ pml, int* __restrict__ ctr) {
  const int S = 2048, H = 12, E = 768;
  const int tid = threadIdx.x;
  const int wave = tid >> 6;
  const int lane = tid & 63;
  const int quad = lane >> 4;
  const int l16 = lane & 15;

  __shared__ __align__(16) __bf16 Ks[64 * 64];     // single-buffer K, swizzled
  __shared__ __align__(16) __bf16 Vt[2][64 * 64];  // dbuf V^T (key-permuted), swizzled
  __shared__ int task;
  __bf16* ep = &Vt[0][0] + wave * 16 * ALDP;  // epilogue buffer aliases Vt (free then)

  const int srow8 = lane >> 3;
  const int csrc = ((lane & 7) ^ srow8) * 8;
  const float SCL = 0.18033688011112042f;  // (1/sqrt(64)) * log2(e)
  const int NTASK = SPLIT ? 24 * 48 : 24 * 32;

  for (;;) {
    if (tid == 0) task = atomicAdd(ctr, 1);
    __syncthreads();
    const int t = task;
    if (t >= NTASK) return;
    int qblk, part, bh;
    if constexpr (SPLIT) {
      const int unit = t / 24;
      bh = t - unit * 24;
      qblk = UQ[unit];
      part = UP[unit];
    } else {
      qblk = 31 - (t / 24);
      bh = t - (t / 24) * 24;
      part = 2;
    }
    const int b = bh / H, h = bh - b * H;
    const int q0 = qblk * 64;
    const int qw = q0 + wave * 16;
    const size_t base = (size_t)b * S * E + (size_t)h * 64;
    const int mid = (qblk + 1) >> 1;
    const int kbgn = (part == 1) ? mid : 0;
    const int kend = (part == 0) ? mid : qblk + 1;

    auto STAGE_K = [&](int kts) {
      const int k0s = kts * 64;
#pragma unroll
      for (int u = 0; u < 2; ++u) {
        const int trow = wave * 16 + u * 8;
        __builtin_amdgcn_global_load_lds(
            (const AS1 void*)(kb + base + (size_t)(k0s + trow + srow8) * E + csrc),
            (AS3 void*)(&Ks[trow * 64]), 16, 0, 0);
      }
    };
    auto STAGE_V = [&](int kts, int buf) {
      const int k0s = kts * 64;
      if constexpr (PRE_T) {
#pragma unroll
        for (int u = 0; u < 2; ++u) {
          const int trow = wave * 16 + u * 8;
          __builtin_amdgcn_global_load_lds(
              (const AS1 void*)(vb + ((size_t)(bh * 64 + trow + srow8)) * S + k0s + csrc),
              (AS3 void*)(&Vt[buf][trow * 64]), 16, 0, 0);
        }
      } else {
#pragma unroll
        for (int u = 0; u < 2; ++u) {
          int i = tid + u * 256;
          int kr = i & 63, dq = i >> 6;
          bf16_8 vv = *(const bf16_8*)(vb + base + (size_t)(k0s + kr) * E + dq * 8);
          const int c = 32 * (kr >> 5) + 8 * ((kr >> 2) & 3) + 4 * ((kr >> 4) & 1) + (kr & 3);
#pragma unroll
          for (int j = 0; j < 8; ++j) {
            int drow = dq * 8 + j;
            Vt[buf][drow * 64 + (((c >> 3) ^ (drow & 7)) * 8) + (c & 7)] = vv[j];
          }
        }
      }
    };

    bf16_8 qf[2];
#pragma unroll
    for (int s = 0; s < 2; ++s)
      qf[s] = *(const bf16_8*)(qb + base + (size_t)(qw + l16) * E + s * 32 + quad * 8);

    f32x4 o[4] = {};
    float mq = -1e30f, lq = 0.f;

    STAGE_K(kbgn);
    STAGE_V(kbgn, 0);
    __syncthreads();  // implicit vmcnt(0): first tile staged
    int cur = 0;

    for (int kt = kbgn; kt < kend; ++kt) {
      const int k0 = kt * 64;

      // S^T = K·Q^T from single-buffered Ks
      f32x4 sc[4] = {};
      __builtin_amdgcn_s_setprio(1);
#pragma unroll
      for (int jj = 0; jj < 4; ++jj)
#pragma unroll
        for (int s = 0; s < 2; ++s) {
          bf16_8 kf = *(const bf16_8*)(
              &Ks[(jj * 16 + l16) * 64 + (((s * 4 + quad) ^ (l16 & 7)) * 8)]);
          sc[jj] = __builtin_amdgcn_mfma_f32_16x16x32_bf16(kf, qf[s], sc[jj], 0, 0, 0);
        }
      __builtin_amdgcn_s_setprio(0);

      __syncthreads();  // #1: all waves done reading Ks (no vm outstanding -> cheap)
      if (kt + 1 < kend) {
        STAGE_K(kt + 1);          // overwrite Ks; drained at barrier #2
        STAGE_V(kt + 1, cur ^ 1);  // Vt[cur^1] consumed one barrier ago
      }

      // softmax (exp2 domain) + causal mask on diagonal tile
#pragma unroll
      for (int jj = 0; jj < 4; ++jj)
#pragma unroll
        for (int r = 0; r < 4; ++r) sc[jj][r] *= SCL;
      if (kt == qblk) {
#pragma unroll
        for (int jj = 0; jj < 4; ++jj)
#pragma unroll
          for (int r = 0; r < 4; ++r)
            if ((k0 + jj * 16 + quad * 4 + r) > (qw + l16)) sc[jj][r] = -1e30f;
      }
      float mj[4];
#pragma unroll
      for (int jj = 0; jj < 4; ++jj)
        mj[jj] = fmaxf(fmaxf(sc[jj][0], sc[jj][1]), fmaxf(sc[jj][2], sc[jj][3]));
      float mx = fmaxf(fmaxf(mj[0], mj[1]), fmaxf(mj[2], mj[3]));
      mx = fmaxf(mx, __shfl_xor(mx, 16));
      mx = fmaxf(mx, __shfl_xor(mx, 32));
      const float mn = fmaxf(mq, mx);
      const float corr = exp2f(mq - mn);
      mq = mn;
      float sj[4];
#pragma unroll
      for (int jj = 0; jj < 4; ++jj) {
#pragma unroll
        for (int r = 0; r < 4; ++r) sc[jj][r] = exp2f(sc[jj][r] - mn);
        sj[jj] = (sc[jj][0] + sc[jj][1]) + (sc[jj][2] + sc[jj][3]);
      }
      float sum = (sj[0] + sj[1]) + (sj[2] + sj[3]);
      sum += __shfl_xor(sum, 16);
      sum += __shfl_xor(sum, 32);
      lq = lq * corr + sum;
#pragma unroll
      for (int nt2 = 0; nt2 < 4; ++nt2)
#pragma unroll
        for (int r = 0; r < 4; ++r) o[nt2][r] *= corr;

      // P fragments in-register (key-permuted to match vt layout)
      bf16_8 pf[2];
#pragma unroll
      for (int s = 0; s < 2; ++s)
#pragma unroll
        for (int r = 0; r < 4; ++r) {
          pf[s][r] = (__bf16)sc[2 * s][r];
          pf[s][4 + r] = (__bf16)sc[2 * s + 1][r];
        }

      // O^T += V^T·P^T
      __builtin_amdgcn_s_setprio(1);
#pragma unroll
      for (int s = 0; s < 2; ++s)
#pragma unroll
        for (int dt = 0; dt < 4; ++dt) {
          bf16_8 vf = *(const bf16_8*)(
              &Vt[cur][(dt * 16 + l16) * 64 + (((s * 4 + quad) ^ (l16 & 7)) * 8)]);
          o[dt] = __builtin_amdgcn_mfma_f32_16x16x32_bf16(vf, pf[s], o[dt], 0, 0, 0);
        }
      __builtin_amdgcn_s_setprio(0);

      __syncthreads();  // #2: drains K/V staging; Vt[cur] free
      cur ^= 1;
    }

    if (SPLIT && part != 2) {
      // unnormalized O^T partial [d][q] (coalesced: 16 consecutive q per quad-row)
      const int cidx = bh * 16 + (qblk - 16);
      float* poT = po + (size_t)cidx * 8192 + part * 4096;
      const int ql = wave * 16 + l16;
#pragma unroll
      for (int dt = 0; dt < 4; ++dt)
#pragma unroll
        for (int r = 0; r < 4; ++r)
          poT[(dt * 16 + quad * 4 + r) * 64 + ql] = o[dt][r];
      if (quad == 0) {
        pml[(size_t)cidx * 256 + part * 128 + ql] = mq;
        pml[(size_t)cidx * 256 + part * 128 + 64 + ql] = lq;
      }
    } else {
      // normalized write via LDS transpose (ep aliases Vt; free after final barrier)
      const float inv = 1.f / lq;
#pragma unroll
      for (int dt = 0; dt < 4; ++dt) {
        bf16_4 o4;
#pragma unroll
        for (int r = 0; r < 4; ++r) o4[r] = (__bf16)(o[dt][r] * inv);
        *(bf16_4*)(&ep[l16 * ALDP + dt * 16 + quad * 4]) = o4;
      }
#pragma unroll
      for (int u = 0; u < 2; ++u) {
        int j = lane + u * 64;
        int ql = j >> 3, ch = j & 7;
        bf16_8 ov = *(const bf16_8*)(&ep[ql * ALDP + ch * 8]);
        *(bf16_8*)(ob + base + (size_t)(qw + ql) * E + ch * 8) = ov;
      }
    }
  }
}

// ---------------------------------------------------------------- combine split-KV partials (coalesced v2)
// Phase A: lane = q -> po reads are 256B-contiguous per instruction; scale into
// f32 LDS T[q][d] stride 65 (bank = (q+d)%32, conflict-free). Phase B: bf16_8 row
// stores (8 x 128B segments per wave).
__global__ __launch_bounds__(256) void attn_combine(
    const float* __restrict__ po, const float* __restrict__ pml,
    __hip_bfloat16* __restrict__ ob) {
  const int S = 2048, H = 12, E = 768;
  const int cidx = blockIdx.x;
  const int bh = cidx >> 4;
  const int qblk = 16 + (cidx & 15);
  const int b = bh / H, h = bh - b * H;
  const int q0 = qblk * 64;
  const size_t base = (size_t)b * S * E + (size_t)h * 64;
  const float* P0 = po + (size_t)cidx * 8192;
  const float* P1 = P0 + 4096;
  const float* ML = pml + (size_t)cidx * 256;

  __shared__ float a1[64], a2[64], dn[64];
  __shared__ float T[64 * 65];
  const int t = threadIdx.x;
  if (t < 64) {
    const float m1 = ML[t], l1 = ML[64 + t];
    const float m2 = ML[128 + t], l2 = ML[192 + t];
    const float ms = fmaxf(m1, m2);
    const float e1 = exp2f(m1 - ms), e2 = exp2f(m2 - ms);
    a1[t] = e1;
    a2[t] = e2;
    dn[t] = 1.f / (e1 * l1 + e2 * l2);
  }
  __syncthreads();
  const int q = t & 63;
  const int w = t >> 6;
#pragma unroll
  for (int i = 0; i < 16; ++i) {
    const int d = w * 16 + i;
    T[q * 65 + d] = (a1[q] * P0[d * 64 + q] + a2[q] * P1[d * 64 + q]) * dn[q];
  }
  __syncthreads();
  const int c8 = t & 7;
  const int qr = t >> 3;  // 0..31
#pragma unroll
  for (int p = 0; p < 2; ++p) {
    const int qq = qr + p * 32;
    bf16_8 ov;
#pragma unroll
    for (int j = 0; j < 8; ++j) ov[j] = (__bf16)T[qq * 65 + c8 * 8 + j];
    *(bf16_8*)(ob + base + (size_t)(q0 + qq) * E + c8 * 8) = ov;
  }
}

// ---------------------------------------------------------------- launch
extern "C" void kernel_launch(void* const* d_in, const int* in_sizes, int n_in,
                              void* d_out, int out_size, void* d_ws, size_t ws_size,
                              hipStream_t stream) {
  const int Bv = 2, S = 2048, E = 768, FF = 3072;
  const int M = Bv * S;  // 4096
  const size_t ME = (size_t)M * E;
  const size_t EE = (size_t)E * E;
  const size_t EF = (size_t)E * FF;

  const float* x = (const float*)d_in[0];
  const float* wq = (const float*)d_in[1];
  const float* wk = (const float*)d_in[2];
  const float* wv = (const float*)d_in[3];
  const float* wo = (const float*)d_in[4];
  const float* bo = (const float*)d_in[5];
  const float* w1 = (const float*)d_in[6];
  const float* b1 = (const float*)d_in[7];
  const float* w2 = (const float*)d_in[8];
  const float* b2 = (const float*)d_in[9];
  const float* gamma = (const float*)d_in[10];
  const float* beta = (const float*)d_in[11];

  // ws: [ctr+256B][s0..s4: 5×ME bf16][s5: w1|w2 bf16 2×EF][pp: 4×ME fp32]
  // Attention phase time-shares pp: vt (6.3 MB), po (12.6 MB), pml (0.4 MB).
  int* ctr = (int*)d_ws;
  __hip_bfloat16* slot = (__hip_bfloat16*)((char*)d_ws + 256);
  __hip_bfloat16* s0 = slot;
  __hip_bfloat16* s1 = slot + ME;
  __hip_bfloat16* s4 = slot + 4 * ME;
  __hip_bfloat16* s5 = slot + 5 * ME;
  float* pp = (float*)(slot + 5 * ME + 2 * EF);
  __hip_bfloat16* vt = (__hip_bfloat16*)pp;
  float* po = (float*)((char*)pp + ME * sizeof(__hip_bfloat16));
  float* pml = po + (size_t)384 * 8192;
  float* res = (float*)d_out;

  const size_t need_mid = 256 + (5 * ME + 2 * EF) * sizeof(__hip_bfloat16);
  const size_t need_full = need_mid + 4 * ME * sizeof(float);
  const bool full = ws_size >= need_full;
  const bool mid = ws_size >= need_mid;

  // 0. weights -> bf16
  cvt_multi<<<dim3(EE / 1024, 4), 256, 0, stream>>>(
      wq, wk, wv, wo, s4, s4 + EE, s4 + 2 * EE, s4 + 3 * EE);
  if (mid)
    cvt_multi<<<dim3(EF / 1024, 2), 256, 0, stream>>>(
        w1, w2, nullptr, nullptr, s5, s5 + EF, nullptr, nullptr);
  // 1. LN1
  ln_kernel<<<M, 256, 0, stream>>>(x, gamma, beta, s0, E);
  // 2. fused Q/K/V projection -> s1,s2,s3
  gemm_bt<0, false><<<dim3(18, 32), 256, 0, stream>>>(s0, s4, nullptr, s1, M, 2304, E, E, E, 0);
  // 3. causal flash attention -> s0 (+ split partials -> po/pml, combined after)
  zero_ctr<<<1, 64, 0, stream>>>(ctr);
  if (full) {
    transpose_v<<<dim3(32, 24), 256, 0, stream>>>(s1 + 2 * ME, vt);
    attn_mfma<true, true><<<1152, 256, 0, stream>>>(s1, s1 + ME, vt, s0, po, pml, ctr);
    attn_combine<<<384, 256, 0, stream>>>(po, pml, s0);
  } else {
    attn_mfma<false, false><<<768, 256, 0, stream>>>(
        s1, s1 + ME, s1 + 2 * ME, s0, nullptr, nullptr, ctr);
  }

  if (full) {
    // 4. attn-proj partials z=4
    gemm_bt<3, false><<<dim3(6, 32, 4), 256, 0, stream>>>(
        s0, s4 + 3 * EE, nullptr, pp, M, E, E, E, E, 0);
    // 5. res = x + Σpp + bo; y = LN2(res) -> s0
    reduce_ln<<<M, 256, 0, stream>>>(x, pp, 4, bo, gamma, beta, res, s0);
    // 6. FFN up + GELU -> s1..s4
    gemm_bt<1, false><<<dim3(24, 32), 256, 0, stream>>>(s0, s5, b1, s1, M, FF, E, E, E, FF);
    // 7. FFN down partials z=4
    gemm_bt<3, false><<<dim3(6, 32, 4), 256, 0, stream>>>(
        s1, s5 + EF, nullptr, pp, M, E, FF, FF, FF, 0);
    // 8. out = res + Σpp + b2
    reduce_out<<<M, 256, 0, stream>>>(pp, 4, b2, res);
  } else {
    hipMemcpyAsync(d_out, x, ME * sizeof(float), hipMemcpyDeviceToDevice, stream);
    gemm_bt<2, false><<<dim3(6, 32, 2), 256, 0, stream>>>(
        s0, s4 + 3 * EE, bo, res, M, E, E, E, E, 0);
    ln_kernel<<<M, 256, 0, stream>>>(res, gamma, beta, s0, E);
    if (mid) {
      gemm_bt<1, false><<<dim3(24, 32), 256, 0, stream>>>(s0, s5, b1, s1, M, FF, E, E, E, FF);
      gemm_bt<2, false><<<dim3(6, 32, 4), 256, 0, stream>>>(
          s1, s5 + EF, b2, res, M, E, FF, FF, FF, 0);
    } else {
      gemm_bt<1, true><<<dim3(24, 32), 256, 0, stream>>>(s0, w1, b1, s1, M, FF, E, E, E, FF);
      cvt_multi<<<dim3(EF / 1024, 1), 256, 0, stream>>>(
          w2, nullptr, nullptr, nullptr, s0, nullptr, nullptr, nullptr);
      gemm_bt<2, false><<<dim3(6, 32, 4), 256, 0, stream>>>(
          s1, s0, b2, res, M, E, FF, FF, FF, 0);
    }
  }
}

// Round 9
// 307.894 us; speedup vs baseline: 1.0677x; 1.0315x over previous
//
#include <hip/hip_runtime.h>
#include <hip/hip_bf16.h>
#include <math.h>

typedef __bf16 bf16_8 __attribute__((ext_vector_type(8)));
typedef __bf16 bf16_4 __attribute__((ext_vector_type(4)));
typedef float f32x4 __attribute__((ext_vector_type(4)));

#define AS1 __attribute__((address_space(1)))
#define AS3 __attribute__((address_space(3)))

// (1/sqrt(64)) * log2(e): folded into Q at QKV-epilogue so attn scores are
// already in exp2 domain.
#define SCL_Q 0.18033688011112042f

// ---------------------------------------------------------------- LayerNorm (fp32 in -> bf16 out)
__global__ __launch_bounds__(256) void ln_kernel(
    const float* __restrict__ x, const float* __restrict__ g,
    const float* __restrict__ b, __hip_bfloat16* __restrict__ out, int cols) {
  const int row = blockIdx.x;
  const int t = threadIdx.x;
  float loc[3];
  float s = 0.f, s2 = 0.f;
#pragma unroll
  for (int i = 0; i < 3; ++i) {
    float v = x[(size_t)row * cols + t + i * 256];
    loc[i] = v;
    s += v;
    s2 += v * v;
  }
#pragma unroll
  for (int off = 32; off; off >>= 1) {
    s += __shfl_down(s, off);
    s2 += __shfl_down(s2, off);
  }
  __shared__ float red[2][4];
  const int lane = t & 63, w = t >> 6;
  if (lane == 0) {
    red[0][w] = s;
    red[1][w] = s2;
  }
  __syncthreads();
  s = red[0][0] + red[0][1] + red[0][2] + red[0][3];
  s2 = red[1][0] + red[1][1] + red[1][2] + red[1][3];
  const float mu = s / cols;
  const float var = s2 / cols - mu * mu;
  const float rs = rsqrtf(var + 1e-5f);
  __hip_bfloat16* orow = out + (size_t)row * cols;
#pragma unroll
  for (int i = 0; i < 3; ++i) {
    int c = t + i * 256;
    orow[c] = __hip_bfloat16((loc[i] - mu) * rs * g[c] + b[c]);
  }
}

// ---------------------------------------------------------------- fused split-K reduce + residual + LN2
__global__ __launch_bounds__(256) void reduce_ln(
    const float* __restrict__ x, const float* __restrict__ part, int nz,
    const float* __restrict__ bias, const float* __restrict__ g,
    const float* __restrict__ b, float* __restrict__ res,
    __hip_bfloat16* __restrict__ yout) {
  const int row = blockIdx.x;
  const int t = threadIdx.x;
  const size_t zstride = (size_t)4096 * 768;
  float loc[3];
  float s = 0.f, s2 = 0.f;
#pragma unroll
  for (int i = 0; i < 3; ++i) {
    const int c = t + i * 256;
    const size_t off = (size_t)row * 768 + c;
    float v = x[off] + bias[c];
    for (int z = 0; z < nz; ++z) v += part[(size_t)z * zstride + off];
    res[off] = v;
    loc[i] = v;
    s += v;
    s2 += v * v;
  }
#pragma unroll
  for (int off = 32; off; off >>= 1) {
    s += __shfl_down(s, off);
    s2 += __shfl_down(s2, off);
  }
  __shared__ float red[2][4];
  const int lane = t & 63, w = t >> 6;
  if (lane == 0) {
    red[0][w] = s;
    red[1][w] = s2;
  }
  __syncthreads();
  s = red[0][0] + red[0][1] + red[0][2] + red[0][3];
  s2 = red[1][0] + red[1][1] + red[1][2] + red[1][3];
  const float mu = s / 768.f;
  const float var = s2 / 768.f - mu * mu;
  const float rs = rsqrtf(var + 1e-5f);
#pragma unroll
  for (int i = 0; i < 3; ++i) {
    const int c = t + i * 256;
    yout[(size_t)row * 768 + c] = __hip_bfloat16((loc[i] - mu) * rs * g[c] + b[c]);
  }
}

// ---------------------------------------------------------------- fused split-K reduce into residual (final out)
__global__ __launch_bounds__(256) void reduce_out(
    const float* __restrict__ part, int nz, const float* __restrict__ bias,
    float* __restrict__ res) {
  const int row = blockIdx.x;
  const int t = threadIdx.x;
  const size_t zstride = (size_t)4096 * 768;
#pragma unroll
  for (int i = 0; i < 3; ++i) {
    const int c = t + i * 256;
    const size_t off = (size_t)row * 768 + c;
    float v = res[off] + bias[c];
    for (int z = 0; z < nz; ++z) v += part[(size_t)z * zstride + off];
    res[off] = v;
  }
}

// ---------------------------------------------------------------- fp32 -> bf16 weight conversion (fallback path)
__global__ __launch_bounds__(256) void cvt_multi(
    const float* __restrict__ sa, const float* __restrict__ sb,
    const float* __restrict__ sc, const float* __restrict__ sd,
    __hip_bfloat16* __restrict__ da, __hip_bfloat16* __restrict__ db,
    __hip_bfloat16* __restrict__ dc, __hip_bfloat16* __restrict__ dd) {
  const float* src;
  __hip_bfloat16* dst;
  if (blockIdx.y == 0) { src = sa; dst = da; }
  else if (blockIdx.y == 1) { src = sb; dst = db; }
  else if (blockIdx.y == 2) { src = sc; dst = dc; }
  else { src = sd; dst = dd; }
  const size_t i = ((size_t)blockIdx.x * 256 + threadIdx.x) * 4;
  float4 f = *(const float4*)(src + i);
  bf16_4 o;
  o[0] = (__bf16)f.x; o[1] = (__bf16)f.y; o[2] = (__bf16)f.z; o[3] = (__bf16)f.w;
  *(bf16_4*)((__bf16*)dst + i) = o;
}

// ---------------------------------------------------------------- all 6 weights -> bf16 in one launch
// grid = 2304 (4 x EE/1024) + 4608 (2 x EF/1024) = 6912 blocks.
__global__ __launch_bounds__(256) void cvt_all(
    const float* __restrict__ wq, const float* __restrict__ wk,
    const float* __restrict__ wv, const float* __restrict__ wo,
    const float* __restrict__ w1, const float* __restrict__ w2,
    __hip_bfloat16* __restrict__ dA, __hip_bfloat16* __restrict__ dF) {
  const size_t EE = 589824, EF = 2359296;
  int bid = blockIdx.x;
  const float* src;
  __hip_bfloat16* dst;
  size_t off;
  if (bid < 2304) {
    const int m = bid / 576;
    off = (size_t)(bid - m * 576) * 1024;
    src = (m == 0) ? wq : (m == 1) ? wk : (m == 2) ? wv : wo;
    dst = dA + (size_t)m * EE;
  } else {
    bid -= 2304;
    const int m = bid / 2304;
    off = (size_t)(bid - m * 2304) * 1024;
    src = m ? w2 : w1;
    dst = dF + (size_t)m * EF;
  }
  const size_t i = off + (size_t)threadIdx.x * 4;
  float4 f = *(const float4*)(src + i);
  bf16_4 o;
  o[0] = (__bf16)f.x; o[1] = (__bf16)f.y; o[2] = (__bf16)f.z; o[3] = (__bf16)f.w;
  *(bf16_4*)((__bf16*)dst + i) = o;
}

// ---------------------------------------------------------------- V pre-transpose + key-permute (frozen)
__global__ __launch_bounds__(256) void transpose_v(
    const __hip_bfloat16* __restrict__ v, __hip_bfloat16* __restrict__ vt) {
  const int S = 2048, E = 768, H = 12;
  const int s0 = blockIdx.x * 64;
  const int bh = blockIdx.y;
  const int b = bh / H, h = bh - b * H;
  __shared__ __align__(16) __bf16 T[64 * 72];
  const int tid = threadIdx.x;
#pragma unroll
  for (int u = 0; u < 2; ++u) {
    int i = tid + u * 256;
    int sr = i >> 3, c = i & 7;
    *(bf16_8*)(&T[sr * 72 + c * 8]) =
        *(const bf16_8*)(v + ((size_t)b * S + s0 + sr) * E + h * 64 + c * 8);
  }
  __syncthreads();
#pragma unroll
  for (int u = 0; u < 2; ++u) {
    int i = tid + u * 256;
    int dr = i >> 3, kc = i & 7;
    bf16_8 o;
#pragma unroll
    for (int e = 0; e < 8; ++e) {
      int k = 32 * (kc >> 2) + 16 * (e >> 2) + 4 * (kc & 3) + (e & 3);
      o[e] = T[k * 72 + dr];
    }
    *(bf16_8*)(vt + ((size_t)bh * 64 + dr) * S + s0 + kc * 8) = o;
  }
}

// ---------------------------------------------------------------- GEMM (round-6 loop + T1 XCD swizzle)
// NEW: XCD-aware tile swizzle — consecutive tiles (sharing the A panel) map to the
// SAME XCD's L2 (tile = (bid%8)*(nwg/8) + bid/8; all grids have nwg%8==0).
// MODE 0 additionally pre-scales the Q slot by SCL_Q (folds attn's softmax scale).
template <int MODE, bool BF32>
__global__ __launch_bounds__(256) void gemm_bt(
    const __hip_bfloat16* __restrict__ A, const void* __restrict__ Bx,
    const float* __restrict__ bias, void* __restrict__ out,
    int M, int N, int K, int lda, int ldb, int ldout) {
  constexpr int BM = 128, BN = 128, BK = 64;
  constexpr int LDBP = BF32 ? 72 : BK;
  __shared__ __align__(16) __bf16 As[BM * BK];
  __shared__ __align__(16) __bf16 Bs[BN * LDBP];
  const int tid = threadIdx.x;

  // T1: XCD-aware swizzle of the flat tile index
  int flat = blockIdx.y * gridDim.x + blockIdx.x;
  const int nwg = gridDim.x * gridDim.y;
  if ((nwg & 7) == 0) flat = (flat & 7) * (nwg >> 3) + (flat >> 3);
  const int m0 = (flat / gridDim.x) * BM;
  const int n0 = (flat % gridDim.x) * BN;

  const int wave = tid >> 6;
  const int lane = tid & 63;
  const int quad = lane >> 4;
  const int l16 = lane & 15;
  const int wm = (wave & 1) * 64;
  const int wn = (wave >> 1) * 64;

  int kbase = 0, kcnt = K;
  if constexpr (MODE == 2 || MODE == 3) {
    kcnt = K / gridDim.z;
    kbase = blockIdx.z * kcnt;
  }

  const int srow = lane >> 3;
  const int scol = ((lane & 7) ^ (srow & 7)) * 8;
  const __hip_bfloat16* Ap = A + (size_t)(m0 + wave * 8 + srow) * lda + kbase + scol;
  const __hip_bfloat16* Bpb = nullptr;
  const float* Bpf = nullptr;
  if constexpr (BF32)
    Bpf = (const float*)Bx;
  else
    Bpb = (const __hip_bfloat16*)Bx + (size_t)(n0 + wave * 8 + srow) * ldb + kbase + scol;

  f32x4 acc[4][4] = {};

  for (int k0 = 0; k0 < kcnt; k0 += BK) {
    __syncthreads();
#pragma unroll
    for (int u = 0; u < 4; ++u) {
      __builtin_amdgcn_global_load_lds(
          (const AS1 void*)(Ap + (size_t)(u * 32) * lda + k0),
          (AS3 void*)(&As[(u * 32 + wave * 8) * BK]), 16, 0, 0);
      if constexpr (!BF32)
        __builtin_amdgcn_global_load_lds(
            (const AS1 void*)(Bpb + (size_t)(u * 32) * ldb + k0),
            (AS3 void*)(&Bs[(u * 32 + wave * 8) * BK]), 16, 0, 0);
    }
    if constexpr (BF32) {
#pragma unroll
      for (int u = 0; u < 4; ++u) {
        int c = u * 256 + tid;
        int row = c >> 3, kc = c & 7;
        const float* src = Bpf + (size_t)(n0 + row) * ldb + kbase + k0 + kc * 8;
        float4 f0 = *(const float4*)src;
        float4 f1 = *(const float4*)(src + 4);
        bf16_8 bv;
        bv[0] = (__bf16)f0.x; bv[1] = (__bf16)f0.y; bv[2] = (__bf16)f0.z; bv[3] = (__bf16)f0.w;
        bv[4] = (__bf16)f1.x; bv[5] = (__bf16)f1.y; bv[6] = (__bf16)f1.z; bv[7] = (__bf16)f1.w;
        *(bf16_8*)(&Bs[row * LDBP + kc * 8]) = bv;
      }
    }
    __syncthreads();
#pragma unroll
    for (int kk = 0; kk < 2; ++kk) {
      bf16_8 af[4], bfr[4];
#pragma unroll
      for (int i = 0; i < 4; ++i)
        af[i] = *(const bf16_8*)(
            &As[(wm + i * 16 + l16) * BK + (((kk * 4 + quad) ^ (l16 & 7)) * 8)]);
#pragma unroll
      for (int j = 0; j < 4; ++j) {
        if constexpr (BF32)
          bfr[j] = *(const bf16_8*)(&Bs[(wn + j * 16 + l16) * LDBP + kk * 32 + quad * 8]);
        else
          bfr[j] = *(const bf16_8*)(
              &Bs[(wn + j * 16 + l16) * BK + (((kk * 4 + quad) ^ (l16 & 7)) * 8)]);
      }
#pragma unroll
      for (int i = 0; i < 4; ++i)
#pragma unroll
        for (int j = 0; j < 4; ++j)
          acc[i][j] =
              __builtin_amdgcn_mfma_f32_16x16x32_bf16(af[i], bfr[j], acc[i][j], 0, 0, 0);
    }
  }

#pragma unroll
  for (int i = 0; i < 4; ++i) {
#pragma unroll
    for (int j = 0; j < 4; ++j) {
#pragma unroll
      for (int r = 0; r < 4; ++r) {
        const int row = m0 + wm + i * 16 + quad * 4 + r;
        const int col = n0 + wn + j * 16 + l16;
        const float v = acc[i][j][r];
        if constexpr (MODE == 0) {
          const int tsel = n0 / 768;
          const size_t idx = ((size_t)tsel * M + row) * 768 + (col - tsel * 768);
          const float vs = (tsel == 0) ? v * SCL_Q : v;  // pre-scale Q slot
          ((__hip_bfloat16*)out)[idx] = __hip_bfloat16(vs);
        } else if constexpr (MODE == 1) {
          float tt = v + bias[col];
          float gl = 0.5f * tt * (1.0f + erff(tt * 0.70710678118654752f));
          ((__hip_bfloat16*)out)[(size_t)row * ldout + col] = __hip_bfloat16(gl);
        } else if constexpr (MODE == 2) {
          float add = v + ((blockIdx.z == 0 && bias) ? bias[col] : 0.f);
          atomicAdd((float*)out + (size_t)row * 768 + col, add);
        } else {
          ((float*)out)[(size_t)blockIdx.z * M * 768 + (size_t)row * 768 + col] = v;
        }
      }
    }
  }
}

// ---------------------------------------------------------------- work counter
__global__ void zero_ctr(int* __restrict__ c) {
  if (threadIdx.x == 0) *c = 0;
}

// ---------------------------------------------------------------- MFMA flash attention, v6
// Round-8 schedule (single-buf K + dbuf V^T, 2 barriers/tile, KV-split) plus:
//  - Q pre-scaled at QKV epilogue (scores arrive in exp2 domain; scale pass deleted)
//  - defer-max (T13): skip {corr, rescale, mq update} unless a lane's tile-max
//    exceeds mq + 11.5 (= 8 nats); P bounded by 2^11.5, safe in bf16/fp32.
#define ALDP 72
__device__ __constant__ signed char UQ[48] = {
    31, 31, 30, 15, 30, 29, 29, 28, 14, 28, 27, 27, 26, 13, 26, 25,
    25, 24, 12, 24, 23, 23, 22, 11, 22, 21, 21, 20, 10, 20, 19, 19,
    18, 9, 18, 17, 17, 16, 8, 16, 7, 6, 5, 4, 3, 2, 1, 0};
__device__ __constant__ signed char UP[48] = {
    0, 1, 1, 2, 0, 0, 1, 1, 2, 0, 0, 1, 1, 2, 0, 0,
    1, 1, 2, 0, 0, 1, 1, 2, 0, 0, 1, 1, 2, 0, 0, 1,
    1, 2, 0, 0, 1, 1, 2, 0, 2, 2, 2, 2, 2, 2, 2, 2};

template <bool PRE_T, bool SPLIT>
__global__ __launch_bounds__(256) void attn_mfma(
    const __hip_bfloat16* __restrict__ qb, const __hip_bfloat16* __restrict__ kb,
    const __hip_bfloat16* __restrict__ vb, __hip_bfloat16* __restrict__ ob,
    float* __restrict__ po, float* __restrict__ pml, int* __restrict__ ctr) {
  const int S = 2048, H = 12, E = 768;
  const int tid = threadIdx.x;
  const int wave = tid >> 6;
  const int lane = tid & 63;
  const int quad = lane >> 4;
  const int l16 = lane & 15;

  __shared__ __align__(16) __bf16 Ks[64 * 64];     // single-buffer K, swizzled
  __shared__ __align__(16) __bf16 Vt[2][64 * 64];  // dbuf V^T (key-permuted), swizzled
  __shared__ int task;
  __bf16* ep = &Vt[0][0] + wave * 16 * ALDP;  // epilogue buffer aliases Vt

  const int srow8 = lane >> 3;
  const int csrc = ((lane & 7) ^ srow8) * 8;
  const int NTASK = SPLIT ? 24 * 48 : 24 * 32;

  for (;;) {
    if (tid == 0) task = atomicAdd(ctr, 1);
    __syncthreads();
    const int t = task;
    if (t >= NTASK) return;
    int qblk, part, bh;
    if constexpr (SPLIT) {
      const int unit = t / 24;
      bh = t - unit * 24;
      qblk = UQ[unit];
      part = UP[unit];
    } else {
      qblk = 31 - (t / 24);
      bh = t - (t / 24) * 24;
      part = 2;
    }
    const int b = bh / H, h = bh - b * H;
    const int q0 = qblk * 64;
    const int qw = q0 + wave * 16;
    const size_t base = (size_t)b * S * E + (size_t)h * 64;
    const int mid = (qblk + 1) >> 1;
    const int kbgn = (part == 1) ? mid : 0;
    const int kend = (part == 0) ? mid : qblk + 1;

    auto STAGE_K = [&](int kts) {
      const int k0s = kts * 64;
#pragma unroll
      for (int u = 0; u < 2; ++u) {
        const int trow = wave * 16 + u * 8;
        __builtin_amdgcn_global_load_lds(
            (const AS1 void*)(kb + base + (size_t)(k0s + trow + srow8) * E + csrc),
            (AS3 void*)(&Ks[trow * 64]), 16, 0, 0);
      }
    };
    auto STAGE_V = [&](int kts, int buf) {
      const int k0s = kts * 64;
      if constexpr (PRE_T) {
#pragma unroll
        for (int u = 0; u < 2; ++u) {
          const int trow = wave * 16 + u * 8;
          __builtin_amdgcn_global_load_lds(
              (const AS1 void*)(vb + ((size_t)(bh * 64 + trow + srow8)) * S + k0s + csrc),
              (AS3 void*)(&Vt[buf][trow * 64]), 16, 0, 0);
        }
      } else {
#pragma unroll
        for (int u = 0; u < 2; ++u) {
          int i = tid + u * 256;
          int kr = i & 63, dq = i >> 6;
          bf16_8 vv = *(const bf16_8*)(vb + base + (size_t)(k0s + kr) * E + dq * 8);
          const int c = 32 * (kr >> 5) + 8 * ((kr >> 2) & 3) + 4 * ((kr >> 4) & 1) + (kr & 3);
#pragma unroll
          for (int j = 0; j < 8; ++j) {
            int drow = dq * 8 + j;
            Vt[buf][drow * 64 + (((c >> 3) ^ (drow & 7)) * 8) + (c & 7)] = vv[j];
          }
        }
      }
    };

    bf16_8 qf[2];
#pragma unroll
    for (int s = 0; s < 2; ++s)
      qf[s] = *(const bf16_8*)(qb + base + (size_t)(qw + l16) * E + s * 32 + quad * 8);

    f32x4 o[4] = {};
    float mq = -1e30f, lq = 0.f;

    STAGE_K(kbgn);
    STAGE_V(kbgn, 0);
    __syncthreads();
    int cur = 0;

    for (int kt = kbgn; kt < kend; ++kt) {
      const int k0 = kt * 64;

      // S^T = K·Q^T (already exp2-domain-scaled via Q)
      f32x4 sc[4] = {};
      __builtin_amdgcn_s_setprio(1);
#pragma unroll
      for (int jj = 0; jj < 4; ++jj)
#pragma unroll
        for (int s = 0; s < 2; ++s) {
          bf16_8 kf = *(const bf16_8*)(
              &Ks[(jj * 16 + l16) * 64 + (((s * 4 + quad) ^ (l16 & 7)) * 8)]);
          sc[jj] = __builtin_amdgcn_mfma_f32_16x16x32_bf16(kf, qf[s], sc[jj], 0, 0, 0);
        }
      __builtin_amdgcn_s_setprio(0);

      __syncthreads();  // #1: all waves done reading Ks
      if (kt + 1 < kend) {
        STAGE_K(kt + 1);
        STAGE_V(kt + 1, cur ^ 1);
      }

      // causal mask on diagonal tile only
      if (kt == qblk) {
#pragma unroll
        for (int jj = 0; jj < 4; ++jj)
#pragma unroll
          for (int r = 0; r < 4; ++r)
            if ((k0 + jj * 16 + quad * 4 + r) > (qw + l16)) sc[jj][r] = -1e30f;
      }
      // per-query tile max (tree + 2 shuffles)
      float mj[4];
#pragma unroll
      for (int jj = 0; jj < 4; ++jj)
        mj[jj] = fmaxf(fmaxf(sc[jj][0], sc[jj][1]), fmaxf(sc[jj][2], sc[jj][3]));
      float pmax = fmaxf(fmaxf(mj[0], mj[1]), fmaxf(mj[2], mj[3]));
      pmax = fmaxf(pmax, __shfl_xor(pmax, 16));
      pmax = fmaxf(pmax, __shfl_xor(pmax, 32));
      // defer-max: only rescale when some lane's max rose past mq + 11.5 bits
      if (!__all(pmax <= mq + 11.5f)) {
        const float mn = fmaxf(mq, pmax);
        const float corr = exp2f(mq - mn);
        mq = mn;
        lq *= corr;
#pragma unroll
        for (int nt2 = 0; nt2 < 4; ++nt2)
#pragma unroll
          for (int r = 0; r < 4; ++r) o[nt2][r] *= corr;
      }
      // exp2 + tree sum
      float sj[4];
#pragma unroll
      for (int jj = 0; jj < 4; ++jj) {
#pragma unroll
        for (int r = 0; r < 4; ++r) sc[jj][r] = exp2f(sc[jj][r] - mq);
        sj[jj] = (sc[jj][0] + sc[jj][1]) + (sc[jj][2] + sc[jj][3]);
      }
      float sum = (sj[0] + sj[1]) + (sj[2] + sj[3]);
      sum += __shfl_xor(sum, 16);
      sum += __shfl_xor(sum, 32);
      lq += sum;

      // P fragments in-register (key-permuted to match vt layout)
      bf16_8 pf[2];
#pragma unroll
      for (int s = 0; s < 2; ++s)
#pragma unroll
        for (int r = 0; r < 4; ++r) {
          pf[s][r] = (__bf16)sc[2 * s][r];
          pf[s][4 + r] = (__bf16)sc[2 * s + 1][r];
        }

      // O^T += V^T·P^T
      __builtin_amdgcn_s_setprio(1);
#pragma unroll
      for (int s = 0; s < 2; ++s)
#pragma unroll
        for (int dt = 0; dt < 4; ++dt) {
          bf16_8 vf = *(const bf16_8*)(
              &Vt[cur][(dt * 16 + l16) * 64 + (((s * 4 + quad) ^ (l16 & 7)) * 8)]);
          o[dt] = __builtin_amdgcn_mfma_f32_16x16x32_bf16(vf, pf[s], o[dt], 0, 0, 0);
        }
      __builtin_amdgcn_s_setprio(0);

      __syncthreads();  // #2: drains K/V staging; Vt[cur] free
      cur ^= 1;
    }

    if (SPLIT && part != 2) {
      const int cidx = bh * 16 + (qblk - 16);
      float* poT = po + (size_t)cidx * 8192 + part * 4096;
      const int ql = wave * 16 + l16;
#pragma unroll
      for (int dt = 0; dt < 4; ++dt)
#pragma unroll
        for (int r = 0; r < 4; ++r)
          poT[(dt * 16 + quad * 4 + r) * 64 + ql] = o[dt][r];
      if (quad == 0) {
        pml[(size_t)cidx * 256 + part * 128 + ql] = mq;
        pml[(size_t)cidx * 256 + part * 128 + 64 + ql] = lq;
      }
    } else {
      const float inv = 1.f / lq;
#pragma unroll
      for (int dt = 0; dt < 4; ++dt) {
        bf16_4 o4;
#pragma unroll
        for (int r = 0; r < 4; ++r) o4[r] = (__bf16)(o[dt][r] * inv);
        *(bf16_4*)(&ep[l16 * ALDP + dt * 16 + quad * 4]) = o4;
      }
#pragma unroll
      for (int u = 0; u < 2; ++u) {
        int j = lane + u * 64;
        int ql = j >> 3, ch = j & 7;
        bf16_8 ov = *(const bf16_8*)(&ep[ql * ALDP + ch * 8]);
        *(bf16_8*)(ob + base + (size_t)(qw + ql) * E + ch * 8) = ov;
      }
    }
  }
}

// ---------------------------------------------------------------- combine split-KV partials (coalesced)
__global__ __launch_bounds__(256) void attn_combine(
    const float* __restrict__ po, const float* __restrict__ pml,
    __hip_bfloat16* __restrict__ ob) {
  const int S = 2048, H = 12, E = 768;
  const int cidx = blockIdx.x;
  const int bh = cidx >> 4;
  const int qblk = 16 + (cidx & 15);
  const int b = bh / H, h = bh - b * H;
  const int q0 = qblk * 64;
  const size_t base = (size_t)b * S * E + (size_t)h * 64;
  const float* P0 = po + (size_t)cidx * 8192;
  const float* P1 = P0 + 4096;
  const float* ML = pml + (size_t)cidx * 256;

  __shared__ float a1[64], a2[64], dn[64];
  __shared__ float T[64 * 65];
  const int t = threadIdx.x;
  if (t < 64) {
    const float m1 = ML[t], l1 = ML[64 + t];
    const float m2 = ML[128 + t], l2 = ML[192 + t];
    const float ms = fmaxf(m1, m2);
    const float e1 = exp2f(m1 - ms), e2 = exp2f(m2 - ms);
    a1[t] = e1;
    a2[t] = e2;
    dn[t] = 1.f / (e1 * l1 + e2 * l2);
  }
  __syncthreads();
  const int q = t & 63;
  const int w = t >> 6;
#pragma unroll
  for (int i = 0; i < 16; ++i) {
    const int d = w * 16 + i;
    T[q * 65 + d] = (a1[q] * P0[d * 64 + q] + a2[q] * P1[d * 64 + q]) * dn[q];
  }
  __syncthreads();
  const int c8 = t & 7;
  const int qr = t >> 3;
#pragma unroll
  for (int p = 0; p < 2; ++p) {
    const int qq = qr + p * 32;
    bf16_8 ov;
#pragma unroll
    for (int j = 0; j < 8; ++j) ov[j] = (__bf16)T[qq * 65 + c8 * 8 + j];
    *(bf16_8*)(ob + base + (size_t)(q0 + qq) * E + c8 * 8) = ov;
  }
}

// ---------------------------------------------------------------- launch
extern "C" void kernel_launch(void* const* d_in, const int* in_sizes, int n_in,
                              void* d_out, int out_size, void* d_ws, size_t ws_size,
                              hipStream_t stream) {
  const int Bv = 2, S = 2048, E = 768, FF = 3072;
  const int M = Bv * S;  // 4096
  const size_t ME = (size_t)M * E;
  const size_t EE = (size_t)E * E;
  const size_t EF = (size_t)E * FF;

  const float* x = (const float*)d_in[0];
  const float* wq = (const float*)d_in[1];
  const float* wk = (const float*)d_in[2];
  const float* wv = (const float*)d_in[3];
  const float* wo = (const float*)d_in[4];
  const float* bo = (const float*)d_in[5];
  const float* w1 = (const float*)d_in[6];
  const float* b1 = (const float*)d_in[7];
  const float* w2 = (const float*)d_in[8];
  const float* b2 = (const float*)d_in[9];
  const float* gamma = (const float*)d_in[10];
  const float* beta = (const float*)d_in[11];

  int* ctr = (int*)d_ws;
  __hip_bfloat16* slot = (__hip_bfloat16*)((char*)d_ws + 256);
  __hip_bfloat16* s0 = slot;
  __hip_bfloat16* s1 = slot + ME;
  __hip_bfloat16* s4 = slot + 4 * ME;
  __hip_bfloat16* s5 = slot + 5 * ME;
  float* pp = (float*)(slot + 5 * ME + 2 * EF);
  __hip_bfloat16* vt = (__hip_bfloat16*)pp;
  float* po = (float*)((char*)pp + ME * sizeof(__hip_bfloat16));
  float* pml = po + (size_t)384 * 8192;
  float* res = (float*)d_out;

  const size_t need_mid = 256 + (5 * ME + 2 * EF) * sizeof(__hip_bfloat16);
  const size_t need_full = need_mid + 4 * ME * sizeof(float);
  const bool full = ws_size >= need_full;
  const bool mid = ws_size >= need_mid;

  // 0. weights -> bf16 (one launch when s5 exists)
  if (mid)
    cvt_all<<<6912, 256, 0, stream>>>(wq, wk, wv, wo, w1, w2, s4, s5);
  else
    cvt_multi<<<dim3(EE / 1024, 4), 256, 0, stream>>>(
        wq, wk, wv, wo, s4, s4 + EE, s4 + 2 * EE, s4 + 3 * EE);
  // 1. LN1
  ln_kernel<<<M, 256, 0, stream>>>(x, gamma, beta, s0, E);
  // 2. fused Q/K/V projection -> s1,s2,s3 (Q pre-scaled by SCL_Q)
  gemm_bt<0, false><<<dim3(18, 32), 256, 0, stream>>>(s0, s4, nullptr, s1, M, 2304, E, E, E, 0);
  // 3. causal flash attention -> s0
  zero_ctr<<<1, 64, 0, stream>>>(ctr);
  if (full) {
    transpose_v<<<dim3(32, 24), 256, 0, stream>>>(s1 + 2 * ME, vt);
    attn_mfma<true, true><<<1152, 256, 0, stream>>>(s1, s1 + ME, vt, s0, po, pml, ctr);
    attn_combine<<<384, 256, 0, stream>>>(po, pml, s0);
  } else {
    attn_mfma<false, false><<<768, 256, 0, stream>>>(
        s1, s1 + ME, s1 + 2 * ME, s0, nullptr, nullptr, ctr);
  }

  if (full) {
    // 4. attn-proj partials z=4
    gemm_bt<3, false><<<dim3(6, 32, 4), 256, 0, stream>>>(
        s0, s4 + 3 * EE, nullptr, pp, M, E, E, E, E, 0);
    // 5. res = x + Σpp + bo; y = LN2(res) -> s0
    reduce_ln<<<M, 256, 0, stream>>>(x, pp, 4, bo, gamma, beta, res, s0);
    // 6. FFN up + GELU -> s1..s4
    gemm_bt<1, false><<<dim3(24, 32), 256, 0, stream>>>(s0, s5, b1, s1, M, FF, E, E, E, FF);
    // 7. FFN down partials z=4
    gemm_bt<3, false><<<dim3(6, 32, 4), 256, 0, stream>>>(
        s1, s5 + EF, nullptr, pp, M, E, FF, FF, FF, 0);
    // 8. out = res + Σpp + b2
    reduce_out<<<M, 256, 0, stream>>>(pp, 4, b2, res);
  } else {
    hipMemcpyAsync(d_out, x, ME * sizeof(float), hipMemcpyDeviceToDevice, stream);
    gemm_bt<2, false><<<dim3(6, 32, 2), 256, 0, stream>>>(
        s0, s4 + 3 * EE, bo, res, M, E, E, E, E, 0);
    ln_kernel<<<M, 256, 0, stream>>>(res, gamma, beta, s0, E);
    if (mid) {
      gemm_bt<1, false><<<dim3(24, 32), 256, 0, stream>>>(s0, s5, b1, s1, M, FF, E, E, E, FF);
      gemm_bt<2, false><<<dim3(6, 32, 4), 256, 0, stream>>>(
          s1, s5 + EF, b2, res, M, E, FF, FF, FF, 0);
    } else {
      gemm_bt<1, true><<<dim3(24, 32), 256, 0, stream>>>(s0, w1, b1, s1, M, FF, E, E, E, FF);
      cvt_multi<<<dim3(EF / 1024, 1), 256, 0, stream>>>(
          w2, nullptr, nullptr, nullptr, s0, nullptr, nullptr, nullptr);
      gemm_bt<2, false><<<dim3(6, 32, 4), 256, 0, stream>>>(
          s1, s0, b2, res, M, E, FF, FF, FF, 0);
    }
  }
}